// Round 1
// baseline (913.373 us; speedup 1.0000x reference)
//
#include <hip/hip_runtime.h>

#define NN 40000
#define SS 16
#define CC 96
#define GG 12
#define CP 100   // padded LDS row stride for [S][C] tiles (100 % 32 = 4 -> distinct banks across rows; 400B % 16 = 0 -> float4-aligned rows)

// ---------------- Kernel A: fused q/k/v projections ----------------
// grid (625, 3): blockIdx.y picks projection; 64 rows/block in 4 passes of 16.
__global__ __launch_bounds__(256) void qkv_kernel(
    const float* __restrict__ q, const float* __restrict__ kx, const float* __restrict__ v,
    const float* __restrict__ Wq, const float* __restrict__ bq, const float* __restrict__ gq, const float* __restrict__ betaq,
    const float* __restrict__ Wk, const float* __restrict__ bk, const float* __restrict__ gk, const float* __restrict__ betak,
    const float* __restrict__ Wv, const float* __restrict__ bv,
    float* __restrict__ outq, float* __restrict__ outk, float* __restrict__ outv)
{
    __shared__ float sW[CC*CC];
    __shared__ float sb[CC], sg[CC], sbeta[CC];
    __shared__ float sx[16*CC];

    const int p = blockIdx.y;
    const float* X; const float* W; const float* b;
    const float* g = nullptr; const float* beta = nullptr;
    float* out;
    if (p == 0)      { X = q;  W = Wq; b = bq; g = gq; beta = betaq; out = outq; }
    else if (p == 1) { X = kx; W = Wk; b = bk; g = gk; beta = betak; out = outk; }
    else             { X = v;  W = Wv; b = bv; out = outv; }

    const int t = threadIdx.x;
    for (int i = t; i < CC*CC/4; i += 256) ((float4*)sW)[i] = ((const float4*)W)[i];
    if (t < CC) { sb[t] = b[t]; if (p < 2) { sg[t] = g[t]; sbeta[t] = beta[t]; } }

    const int s = t >> 4, c16 = t & 15, c0 = 6*c16;
    const int base = blockIdx.x * 64;

    for (int pass = 0; pass < 4; ++pass) {
        const int row0 = base + pass*16;
        __syncthreads();                       // pass 0: covers sW staging; later: protects sx reuse
        for (int i = t; i < 16*CC/4; i += 256)
            ((float4*)sx)[i] = ((const float4*)(X + (size_t)row0*CC))[i];
        __syncthreads();

        float acc[6];
        #pragma unroll
        for (int j = 0; j < 6; ++j) acc[j] = sb[c0+j];
        const float* xr = sx + s*CC;
        for (int kk = 0; kk < CC; ++kk) {
            float a = xr[kk];
            const float2* w2 = (const float2*)(sW + kk*CC + c0);   // c0 even -> 8B aligned
            float2 wa = w2[0], wb = w2[1], wc = w2[2];
            acc[0] += a*wa.x; acc[1] += a*wa.y;
            acc[2] += a*wb.x; acc[3] += a*wb.y;
            acc[4] += a*wc.x; acc[5] += a*wc.y;
        }
        if (p < 2) {  // LayerNorm over 96 + ReLU (16 threads/row, shuffle width 16)
            float sum = 0.f, sq2 = 0.f;
            #pragma unroll
            for (int j = 0; j < 6; ++j) { sum += acc[j]; sq2 += acc[j]*acc[j]; }
            #pragma unroll
            for (int m = 1; m < 16; m <<= 1) { sum += __shfl_xor(sum, m, 16); sq2 += __shfl_xor(sq2, m, 16); }
            float mu  = sum * (1.f/96.f);
            float var = sq2 * (1.f/96.f) - mu*mu;
            float rs  = rsqrtf(var + 1e-5f);
            #pragma unroll
            for (int j = 0; j < 6; ++j) {
                float y = (acc[j]-mu)*rs*sg[c0+j] + sbeta[c0+j];
                acc[j] = fmaxf(y, 0.f);
            }
        }
        float* orow = out + (size_t)(row0+s)*CC + c0;
        #pragma unroll
        for (int j = 0; j < 6; ++j) orow[j] = acc[j];
    }
}

// ---------------- Kernel B: fused grouped vector attention ----------------
// 1 block = 16 nodes (processed sequentially, weights stay resident in LDS).
__global__ __launch_bounds__(256) void attn_kernel(
    const float* __restrict__ xyz, const int* __restrict__ refidx,
    const float* __restrict__ Wp1, const float* __restrict__ bp1,
    const float* __restrict__ gp,  const float* __restrict__ betap,
    const float* __restrict__ Wp2, const float* __restrict__ bp2,
    const float* __restrict__ Ww1, const float* __restrict__ bw1,
    const float* __restrict__ gw,  const float* __restrict__ betaw,
    const float* __restrict__ Ww2, const float* __restrict__ bw2,
    const float* __restrict__ queryw, const float* __restrict__ keyw, const float* __restrict__ valw,
    float* __restrict__ out)
{
    __shared__ float sWp2[CC*CC];          // 36 KB
    __shared__ float sWw1[CC*GG];          // 4.5 KB
    __shared__ float sWp1[3*CC];
    __shared__ float sWw2[GG*GG];
    __shared__ float sbp1[CC], sgp[CC], sbetap[CC], sbp2[CC];
    __shared__ float sbw1[GG], sgw[GG], sbetaw[GG], sbw2[GG];
    __shared__ float sq[CC];
    __shared__ float skg[SS*CP];           // keyg -> rel (in place)
    __shared__ float svg[SS*CP];           // valg -> valg+peb (in place)
    __shared__ float st1[SS*CP];           // relu(ln(pos@Wp1))
    __shared__ float spos[SS][4];
    __shared__ float sy[SS][GG];
    __shared__ float sw2[SS][GG];
    __shared__ int   sidx[SS];
    __shared__ float smask[SS];

    const int t = threadIdx.x;
    for (int i = t; i < CC*CC/4; i += 256) ((float4*)sWp2)[i] = ((const float4*)Wp2)[i];
    for (int i = t; i < CC*GG/4; i += 256) ((float4*)sWw1)[i] = ((const float4*)Ww1)[i];
    if (t < 3*CC/4)  ((float4*)sWp1)[t] = ((const float4*)Wp1)[t];
    if (t < GG*GG/4) ((float4*)sWw2)[t] = ((const float4*)Ww2)[t];
    if (t < CC) { sbp1[t]=bp1[t]; sgp[t]=gp[t]; sbetap[t]=betap[t]; sbp2[t]=bp2[t]; }
    if (t < GG) { sbw1[t]=bw1[t]; sgw[t]=gw[t]; sbetaw[t]=betaw[t]; sbw2[t]=bw2[t]; }

    const int s = t >> 4, c16 = t & 15, c0 = 6*c16;
    const int g = (c16 < GG) ? c16 : (GG-1);     // clamped to avoid OOB LDS reads in idle lanes

    for (int nn = 0; nn < 16; ++nn) {
        const int n = blockIdx.x * 16 + nn;
        __syncthreads();   // covers weight staging on nn=0; protects buffer reuse after
        if (t < SS) {
            int id = refidx[n*SS + t];
            smask[t] = (id >= 0) ? 1.f : 0.f;
            sidx[t]  = (id < 0) ? 0 : id;
        }
        if (t < CC/4) ((float4*)sq)[t] = ((const float4*)(queryw + (size_t)n*CC))[t];
        __syncthreads();
        if (t < SS) {
            int id = sidx[t]; float m = smask[t];
            spos[t][0] = (xyz[id*3+0] - xyz[n*3+0]) * m;
            spos[t][1] = (xyz[id*3+1] - xyz[n*3+1]) * m;
            spos[t][2] = (xyz[id*3+2] - xyz[n*3+2]) * m;
        }
        for (int i = t; i < SS*CC/4; i += 256) {   // gather keyf/val rows (float4)
            int ss2 = i / (CC/4), f4 = i % (CC/4);
            float m = smask[ss2];
            int src = sidx[ss2];
            float4 kv = ((const float4*)(keyw + (size_t)src*CC))[f4];
            float4 vv = ((const float4*)(valw + (size_t)src*CC))[f4];
            ((float4*)(skg + ss2*CP))[f4] = make_float4(kv.x*m, kv.y*m, kv.z*m, kv.w*m);
            ((float4*)(svg + ss2*CP))[f4] = make_float4(vv.x*m, vv.y*m, vv.z*m, vv.w*m);
        }
        __syncthreads();

        // t1 = relu(ln(pos @ Wp1 + bp1))
        {
            float p0 = spos[s][0], p1 = spos[s][1], p2 = spos[s][2];
            float tv[6];
            #pragma unroll
            for (int j = 0; j < 6; ++j) {
                int c = c0 + j;
                tv[j] = sbp1[c] + p0*sWp1[c] + p1*sWp1[CC+c] + p2*sWp1[2*CC+c];
            }
            float sum = 0.f, sq2 = 0.f;
            #pragma unroll
            for (int j = 0; j < 6; ++j) { sum += tv[j]; sq2 += tv[j]*tv[j]; }
            #pragma unroll
            for (int m2 = 1; m2 < 16; m2 <<= 1) { sum += __shfl_xor(sum, m2, 16); sq2 += __shfl_xor(sq2, m2, 16); }
            float mu  = sum * (1.f/96.f);
            float var = sq2 * (1.f/96.f) - mu*mu;
            float rs  = rsqrtf(var + 1e-5f);
            #pragma unroll
            for (int j = 0; j < 6; ++j) {
                int c = c0 + j;
                st1[s*CP + c] = fmaxf((tv[j]-mu)*rs*sgp[c] + sbetap[c], 0.f);
            }
        }
        __syncthreads();

        // peb = t1 @ Wp2 + bp2; rel = keyg - query + peb (in skg); valg += peb (in svg)
        {
            float acc[6];
            #pragma unroll
            for (int j = 0; j < 6; ++j) acc[j] = sbp2[c0+j];
            const float* t1r = st1 + s*CP;
            for (int kk = 0; kk < CC; ++kk) {
                float a = t1r[kk];
                const float2* w2 = (const float2*)(sWp2 + kk*CC + c0);
                float2 wa = w2[0], wb = w2[1], wc = w2[2];
                acc[0] += a*wa.x; acc[1] += a*wa.y;
                acc[2] += a*wb.x; acc[3] += a*wb.y;
                acc[4] += a*wc.x; acc[5] += a*wc.y;
            }
            #pragma unroll
            for (int j = 0; j < 6; ++j) {
                int c = c0 + j;
                skg[s*CP + c] = skg[s*CP + c] - sq[c] + acc[j];
                svg[s*CP + c] += acc[j];
            }
        }
        __syncthreads();

        // t2 = rel @ Ww1 + bw1 -> LN(12) -> relu -> sy
        {
            float t2 = sbw1[g];
            const float* rr = skg + s*CP;
            for (int kk = 0; kk < CC; ++kk)
                t2 += rr[kk] * sWw1[kk*GG + g];
            float vv = (c16 < GG) ? t2 : 0.f;
            float sum = vv, sq2 = vv*vv;
            #pragma unroll
            for (int m2 = 1; m2 < 16; m2 <<= 1) { sum += __shfl_xor(sum, m2, 16); sq2 += __shfl_xor(sq2, m2, 16); }
            float mu  = sum * (1.f/12.f);
            float var = sq2 * (1.f/12.f) - mu*mu;
            float rs  = rsqrtf(var + 1e-5f);
            float y = (t2-mu)*rs*sgw[g] + sbetaw[g];
            if (c16 < GG) sy[s][g] = fmaxf(y, 0.f);
        }
        __syncthreads();

        // w = sy @ Ww2 + bw2
        if (c16 < GG) {
            float wv = sbw2[g];
            #pragma unroll
            for (int gg2 = 0; gg2 < GG; ++gg2)
                wv += sy[s][gg2] * sWw2[gg2*GG + g];
            sw2[s][g] = wv;
        }
        __syncthreads();

        // softmax over neighbors (axis s) per group, then * mask
        if (t < GG) {
            float mx = -1e30f;
            #pragma unroll
            for (int ss2 = 0; ss2 < SS; ++ss2) mx = fmaxf(mx, sw2[ss2][t]);
            float e[SS]; float tot = 0.f;
            #pragma unroll
            for (int ss2 = 0; ss2 < SS; ++ss2) { e[ss2] = __expf(sw2[ss2][t]-mx); tot += e[ss2]; }
            float inv = 1.f/tot;
            #pragma unroll
            for (int ss2 = 0; ss2 < SS; ++ss2) sw2[ss2][t] = e[ss2]*inv*smask[ss2];
        }
        __syncthreads();

        // out[n][c] = sum_s valg[s][c] * w[s][c/8]
        if (t < CC) {
            int gg2 = t >> 3;
            float acc = 0.f;
            #pragma unroll
            for (int ss2 = 0; ss2 < SS; ++ss2)
                acc += svg[ss2*CP + t] * sw2[ss2][gg2];
            out[(size_t)n*CC + t] = acc;
        }
    }
}

extern "C" void kernel_launch(void* const* d_in, const int* in_sizes, int n_in,
                              void* d_out, int out_size, void* d_ws, size_t ws_size,
                              hipStream_t stream)
{
    const float* q     = (const float*)d_in[0];
    const float* k     = (const float*)d_in[1];
    const float* v     = (const float*)d_in[2];
    const float* xyz   = (const float*)d_in[3];
    const int*   ridx  = (const int*)d_in[4];
    const float* Wq    = (const float*)d_in[5];
    const float* bq    = (const float*)d_in[6];
    const float* gq    = (const float*)d_in[7];
    const float* betaq = (const float*)d_in[8];
    const float* Wk    = (const float*)d_in[9];
    const float* bk    = (const float*)d_in[10];
    const float* gk    = (const float*)d_in[11];
    const float* betak = (const float*)d_in[12];
    const float* Wv    = (const float*)d_in[13];
    const float* bv    = (const float*)d_in[14];
    const float* Wp1   = (const float*)d_in[15];
    const float* bp1   = (const float*)d_in[16];
    const float* gp    = (const float*)d_in[17];
    const float* betap = (const float*)d_in[18];
    const float* Wp2   = (const float*)d_in[19];
    const float* bp2   = (const float*)d_in[20];
    const float* Ww1   = (const float*)d_in[21];
    const float* bw1   = (const float*)d_in[22];
    const float* gw    = (const float*)d_in[23];
    const float* betaw = (const float*)d_in[24];
    const float* Ww2   = (const float*)d_in[25];
    const float* bw2   = (const float*)d_in[26];
    float* out = (float*)d_out;

    float* ws = (float*)d_ws;
    float* queryw = ws;                           // [N, C]
    float* keyw   = ws + (size_t)NN*CC;           // [N, C]
    float* valw   = ws + 2*(size_t)NN*CC;         // [N, C]  (total 46.08 MB)

    qkv_kernel<<<dim3(625, 3, 1), 256, 0, stream>>>(
        q, k, v, Wq, bq, gq, betaq, Wk, bk, gk, betak, Wv, bv,
        queryw, keyw, valw);

    attn_kernel<<<dim3(2500, 1, 1), 256, 0, stream>>>(
        xyz, ridx, Wp1, bp1, gp, betap, Wp2, bp2,
        Ww1, bw1, gw, betaw, Ww2, bw2,
        queryw, keyw, valw, out);
}

// Round 2
// 435.155 us; speedup vs baseline: 2.0990x; 2.0990x over previous
//
#include <hip/hip_runtime.h>

#define NN 40000
#define SS 16
#define CC 96
#define GG 12
#define CP 100   // padded LDS row stride (floats) for per-wave [16][96] buffers

typedef __attribute__((ext_vector_type(8))) short bf16x8;
typedef __attribute__((ext_vector_type(4))) float f32x4;

// float -> bf16 (RNE), returned as raw 16-bit pattern in short
__device__ __forceinline__ short f2bf(float f) {
    union { float f; unsigned u; } c; c.f = f;
    unsigned r = (c.u + 0x7fffu + ((c.u >> 16) & 1u)) >> 16;
    return (short)r;
}

// ---------------- Kernel A: fused q/k/v projections via MFMA ----------------
// grid (Gx, 3). One wave computes a 16-row tile: C[16x96] = X[16x96] @ W[96x96].
// A-frag: lane holds row m=lane&15, k = kb*32 + quad*8 + j.
// C/D:    lane holds col nt*16+(lane&15), rows quad*4 + r.
__global__ __launch_bounds__(256) void qkv_mfma(
    const float* __restrict__ q, const float* __restrict__ kx, const float* __restrict__ v,
    const float* __restrict__ Wq, const float* __restrict__ bq, const float* __restrict__ gq, const float* __restrict__ betaq,
    const float* __restrict__ Wk, const float* __restrict__ bk, const float* __restrict__ gk, const float* __restrict__ betak,
    const float* __restrict__ Wv, const float* __restrict__ bv,
    float* __restrict__ outq, float* __restrict__ outk, float* __restrict__ outv)
{
    __shared__ float sbias[CC], sg[CC], sbeta[CC];

    const int p = blockIdx.y;
    const float* X; const float* W; const float* b;
    const float* g = nullptr; const float* beta = nullptr;
    float* out;
    if (p == 0)      { X = q;  W = Wq; b = bq; g = gq; beta = betaq; out = outq; }
    else if (p == 1) { X = kx; W = Wk; b = bk; g = gk; beta = betak; out = outk; }
    else             { X = v;  W = Wv; b = bv; out = outv; }
    const bool has_ln = (p < 2);

    const int t = threadIdx.x;
    if (t < CC) {
        sbias[t] = b[t];
        if (has_ln) { sg[t] = g[t]; sbeta[t] = beta[t]; }
    }

    const int lane = t & 63, w = t >> 6;
    const int c16 = lane & 15, quad = lane >> 4;

    // B-fragments for W (bf16), held in registers for the whole kernel.
    bf16x8 Wf[6][3];
    #pragma unroll
    for (int nt = 0; nt < 6; ++nt)
        #pragma unroll
        for (int kb = 0; kb < 3; ++kb)
            #pragma unroll
            for (int j = 0; j < 8; ++j)
                Wf[nt][kb][j] = f2bf(W[(size_t)(kb*32 + quad*8 + j)*CC + nt*16 + c16]);

    __syncthreads();

    const f32x4 zero4 = {0.f, 0.f, 0.f, 0.f};

    for (int tile = blockIdx.x*4 + w; tile < NN/16; tile += gridDim.x*4) {
        const int row0 = tile * 16;
        // A-fragments: row c16, cols kb*32+quad*8+j
        const float* xr = X + (size_t)(row0 + c16)*CC;
        bf16x8 Af[3];
        #pragma unroll
        for (int kb = 0; kb < 3; ++kb) {
            const float4 a0 = *(const float4*)(xr + kb*32 + quad*8);
            const float4 a1 = *(const float4*)(xr + kb*32 + quad*8 + 4);
            Af[kb][0] = f2bf(a0.x); Af[kb][1] = f2bf(a0.y);
            Af[kb][2] = f2bf(a0.z); Af[kb][3] = f2bf(a0.w);
            Af[kb][4] = f2bf(a1.x); Af[kb][5] = f2bf(a1.y);
            Af[kb][6] = f2bf(a1.z); Af[kb][7] = f2bf(a1.w);
        }

        f32x4 acc[6];
        #pragma unroll
        for (int nt = 0; nt < 6; ++nt) acc[nt] = zero4;
        #pragma unroll
        for (int kb = 0; kb < 3; ++kb)
            #pragma unroll
            for (int nt = 0; nt < 6; ++nt)
                acc[nt] = __builtin_amdgcn_mfma_f32_16x16x32_bf16(Af[kb], Wf[nt][kb], acc[nt], 0, 0, 0);

        // + bias
        #pragma unroll
        for (int nt = 0; nt < 6; ++nt) {
            const float bb = sbias[nt*16 + c16];
            #pragma unroll
            for (int r = 0; r < 4; ++r) acc[nt][r] += bb;
        }

        if (has_ln) {
            #pragma unroll
            for (int r = 0; r < 4; ++r) {
                float sum = 0.f, sq = 0.f;
                #pragma unroll
                for (int nt = 0; nt < 6; ++nt) { float x = acc[nt][r]; sum += x; sq += x*x; }
                #pragma unroll
                for (int msk = 1; msk < 16; msk <<= 1) {
                    sum += __shfl_xor(sum, msk, 64);
                    sq  += __shfl_xor(sq,  msk, 64);
                }
                const float mu  = sum * (1.f/96.f);
                const float var = sq * (1.f/96.f) - mu*mu;
                const float rs  = rsqrtf(var + 1e-5f);
                #pragma unroll
                for (int nt = 0; nt < 6; ++nt) {
                    const int c = nt*16 + c16;
                    acc[nt][r] = fmaxf((acc[nt][r] - mu)*rs*sg[c] + sbeta[c], 0.f);
                }
            }
        }

        #pragma unroll
        for (int r = 0; r < 4; ++r)
            #pragma unroll
            for (int nt = 0; nt < 6; ++nt)
                out[(size_t)(row0 + quad*4 + r)*CC + nt*16 + c16] = acc[nt][r];
    }
}

// ---------------- Kernel B: grouped vector attention, one node per wave ----------------
__global__ __launch_bounds__(256) void attn_mfma(
    const float* __restrict__ xyz, const int* __restrict__ refidx,
    const float* __restrict__ Wp1, const float* __restrict__ bp1,
    const float* __restrict__ gp,  const float* __restrict__ betap,
    const float* __restrict__ Wp2, const float* __restrict__ bp2,
    const float* __restrict__ Ww1, const float* __restrict__ bw1,
    const float* __restrict__ gw,  const float* __restrict__ betaw,
    const float* __restrict__ Ww2, const float* __restrict__ bw2,
    const float* __restrict__ queryw, const float* __restrict__ keyw, const float* __restrict__ valw,
    float* __restrict__ out)
{
    __shared__ float sWp1[3*CC];
    __shared__ float sbp1[CC], sgp[CC], sbetap[CC], sbp2[CC];
    __shared__ float sWw2[GG*GG];
    __shared__ float sbw1[16], sgw[16], sbetaw[16], sbw2[16];
    __shared__ float pebbuf[4][SS*CP];   // per-wave [16 rows][96 cols] fp32, stride 100
    __shared__ float ybuf[4][SS*GG];     // per-wave y = relu(ln(t2)) [16][12]

    const int t = threadIdx.x;
    for (int i = t; i < 3*CC; i += 256) sWp1[i] = Wp1[i];
    if (t < CC) { sbp1[t] = bp1[t]; sgp[t] = gp[t]; sbetap[t] = betap[t]; sbp2[t] = bp2[t]; }
    if (t < GG*GG) sWw2[t] = Ww2[t];
    if (t < 16) {
        sbw1[t]   = (t < GG) ? bw1[t]   : 0.f;
        sgw[t]    = (t < GG) ? gw[t]    : 0.f;
        sbetaw[t] = (t < GG) ? betaw[t] : 0.f;
        sbw2[t]   = (t < GG) ? bw2[t]   : 0.f;
    }

    const int lane = t & 63, w = t >> 6;
    const int c16 = lane & 15, quad = lane >> 4;

    // B-fragments: Wp2 (6 col-tiles x 3 k-blocks), Ww1 (1 col-tile padded to 16, 3 k-blocks)
    bf16x8 Wp2f[6][3], Ww1f[3];
    #pragma unroll
    for (int nt = 0; nt < 6; ++nt)
        #pragma unroll
        for (int kb = 0; kb < 3; ++kb)
            #pragma unroll
            for (int j = 0; j < 8; ++j)
                Wp2f[nt][kb][j] = f2bf(Wp2[(size_t)(kb*32 + quad*8 + j)*CC + nt*16 + c16]);
    #pragma unroll
    for (int kb = 0; kb < 3; ++kb)
        #pragma unroll
        for (int j = 0; j < 8; ++j)
            Ww1f[kb][j] = (c16 < GG) ? f2bf(Ww1[(size_t)(kb*32 + quad*8 + j)*GG + c16]) : (short)0;

    __syncthreads();   // params staged; everything below is wave-synchronous

    float* peb = pebbuf[w];
    float* yb  = ybuf[w];
    const f32x4 zero4 = {0.f, 0.f, 0.f, 0.f};

    for (int i = 0; i < 4; ++i) {
        const int n = blockIdx.x*16 + w*4 + i;   // one node per wave-iteration

        // this lane's neighbor: s = c16 (quads duplicate)
        const int   id   = refidx[n*SS + c16];
        const float m    = (id >= 0) ? 1.f : 0.f;
        const int   safe = (id < 0) ? 0 : id;

        const float px = (xyz[(size_t)safe*3 + 0] - xyz[(size_t)n*3 + 0]) * m;
        const float py = (xyz[(size_t)safe*3 + 1] - xyz[(size_t)n*3 + 1]) * m;
        const float pz = (xyz[(size_t)safe*3 + 2] - xyz[(size_t)n*3 + 2]) * m;

        // ---- t1 = relu(ln(pos @ Wp1 + bp1)), computed directly in A-frag layout ----
        float tv[3][8];
        float sum = 0.f, sq = 0.f;
        #pragma unroll
        for (int kb = 0; kb < 3; ++kb)
            #pragma unroll
            for (int j = 0; j < 8; ++j) {
                const int c = kb*32 + quad*8 + j;
                const float x = sbp1[c] + px*sWp1[c] + py*sWp1[CC + c] + pz*sWp1[2*CC + c];
                tv[kb][j] = x; sum += x; sq += x*x;
            }
        sum += __shfl_xor(sum, 16, 64); sq += __shfl_xor(sq, 16, 64);
        sum += __shfl_xor(sum, 32, 64); sq += __shfl_xor(sq, 32, 64);
        {
            const float mu  = sum * (1.f/96.f);
            const float var = sq * (1.f/96.f) - mu*mu;
            const float rs  = rsqrtf(var + 1e-5f);
            bf16x8 t1A[3];
            #pragma unroll
            for (int kb = 0; kb < 3; ++kb)
                #pragma unroll
                for (int j = 0; j < 8; ++j) {
                    const int c = kb*32 + quad*8 + j;
                    t1A[kb][j] = f2bf(fmaxf((tv[kb][j] - mu)*rs*sgp[c] + sbetap[c], 0.f));
                }

            // ---- peb = t1 @ Wp2 + bp2 (MFMA) ----
            f32x4 acc[6];
            #pragma unroll
            for (int nt = 0; nt < 6; ++nt) acc[nt] = zero4;
            #pragma unroll
            for (int kb = 0; kb < 3; ++kb)
                #pragma unroll
                for (int nt = 0; nt < 6; ++nt)
                    acc[nt] = __builtin_amdgcn_mfma_f32_16x16x32_bf16(t1A[kb], Wp2f[nt][kb], acc[nt], 0, 0, 0);

            // write peb to per-wave LDS (C/D layout -> row-major), +bp2
            #pragma unroll
            for (int nt = 0; nt < 6; ++nt) {
                const float b2 = sbp2[nt*16 + c16];
                #pragma unroll
                for (int r = 0; r < 4; ++r)
                    peb[(quad*4 + r)*CP + nt*16 + c16] = acc[nt][r] + b2;
            }
        }

        // ---- read peb back in A-layout; gather keyg/valg/query; build rel, vp ----
        float pebA[3][8], vgA[3][8];
        bf16x8 relA[3];
        const float* kr = keyw   + (size_t)safe*CC;
        const float* vr = valw   + (size_t)safe*CC;
        const float* qr = queryw + (size_t)n*CC;
        #pragma unroll
        for (int kb = 0; kb < 3; ++kb) {
            const int off = kb*32 + quad*8;
            const float4 p0 = *(const float4*)(peb + c16*CP + off);
            const float4 p1 = *(const float4*)(peb + c16*CP + off + 4);
            pebA[kb][0]=p0.x; pebA[kb][1]=p0.y; pebA[kb][2]=p0.z; pebA[kb][3]=p0.w;
            pebA[kb][4]=p1.x; pebA[kb][5]=p1.y; pebA[kb][6]=p1.z; pebA[kb][7]=p1.w;
            const float4 k0 = *(const float4*)(kr + off);
            const float4 k1 = *(const float4*)(kr + off + 4);
            const float4 q0 = *(const float4*)(qr + off);
            const float4 q1 = *(const float4*)(qr + off + 4);
            const float4 v0 = *(const float4*)(vr + off);
            const float4 v1 = *(const float4*)(vr + off + 4);
            relA[kb][0] = f2bf(k0.x*m - q0.x + pebA[kb][0]);
            relA[kb][1] = f2bf(k0.y*m - q0.y + pebA[kb][1]);
            relA[kb][2] = f2bf(k0.z*m - q0.z + pebA[kb][2]);
            relA[kb][3] = f2bf(k0.w*m - q0.w + pebA[kb][3]);
            relA[kb][4] = f2bf(k1.x*m - q1.x + pebA[kb][4]);
            relA[kb][5] = f2bf(k1.y*m - q1.y + pebA[kb][5]);
            relA[kb][6] = f2bf(k1.z*m - q1.z + pebA[kb][6]);
            relA[kb][7] = f2bf(k1.w*m - q1.w + pebA[kb][7]);
            vgA[kb][0] = v0.x*m + pebA[kb][0];
            vgA[kb][1] = v0.y*m + pebA[kb][1];
            vgA[kb][2] = v0.z*m + pebA[kb][2];
            vgA[kb][3] = v0.w*m + pebA[kb][3];
            vgA[kb][4] = v1.x*m + pebA[kb][4];
            vgA[kb][5] = v1.y*m + pebA[kb][5];
            vgA[kb][6] = v1.z*m + pebA[kb][6];
            vgA[kb][7] = v1.w*m + pebA[kb][7];
        }

        // ---- t2 = rel @ Ww1 + bw1 (MFMA, cols 12..15 zero-padded) ----
        f32x4 t2 = zero4;
        #pragma unroll
        for (int kb = 0; kb < 3; ++kb)
            t2 = __builtin_amdgcn_mfma_f32_16x16x32_bf16(relA[kb], Ww1f[kb], t2, 0, 0, 0);
        const float bw1v = sbw1[c16];   // 0 for c16 >= 12
        #pragma unroll
        for (int r = 0; r < 4; ++r) t2[r] += bw1v;

        // ---- LN over G=12 per row (C/D layout: lane=col g, rows quad*4+r) ----
        float s1[4], s2[4];
        #pragma unroll
        for (int r = 0; r < 4; ++r) {
            const float x = (c16 < GG) ? t2[r] : 0.f;
            s1[r] = x; s2[r] = x*x;
        }
        #pragma unroll
        for (int msk = 1; msk < 16; msk <<= 1)
            #pragma unroll
            for (int r = 0; r < 4; ++r) {
                s1[r] += __shfl_xor(s1[r], msk, 64);
                s2[r] += __shfl_xor(s2[r], msk, 64);
            }
        #pragma unroll
        for (int r = 0; r < 4; ++r) {
            const float mu  = s1[r] * (1.f/12.f);
            const float var = s2[r] * (1.f/12.f) - mu*mu;
            const float rs  = rsqrtf(var + 1e-5f);
            const float y   = fmaxf((t2[r] - mu)*rs*sgw[c16] + sbetaw[c16], 0.f);
            if (c16 < GG) yb[(quad*4 + r)*GG + c16] = y;
        }

        // ---- w3 = y @ Ww2 + bw2; lane computes s=c16, g' in {quad, quad+4, quad+8} ----
        float w3[3];
        #pragma unroll
        for (int gi = 0; gi < 3; ++gi) {
            const int gpp = quad + gi*4;
            float a2 = sbw2[gpp];
            #pragma unroll
            for (int gg2 = 0; gg2 < GG; ++gg2)
                a2 += yb[c16*GG + gg2] * sWw2[gg2*GG + gpp];
            w3[gi] = a2;
        }

        // ---- softmax over s (the 16 c16-lanes of this quad), then * mask ----
        #pragma unroll
        for (int gi = 0; gi < 3; ++gi) {
            float mx = w3[gi];
            #pragma unroll
            for (int msk = 1; msk < 16; msk <<= 1) mx = fmaxf(mx, __shfl_xor(mx, msk, 64));
            const float e = __expf(w3[gi] - mx);
            float tot = e;
            #pragma unroll
            for (int msk = 1; msk < 16; msk <<= 1) tot += __shfl_xor(tot, msk, 64);
            w3[gi] = e / tot * m;
        }

        // ---- out[c] = sum_s vp[s][c] * w[s][g(c)];  g(c)=c/8 = kb*4+quad ----
        #pragma unroll
        for (int kb = 0; kb < 3; ++kb) {
            float ov[8];
            #pragma unroll
            for (int j = 0; j < 8; ++j) {
                float pr = vgA[kb][j] * w3[kb];
                pr += __shfl_xor(pr, 1, 64);
                pr += __shfl_xor(pr, 2, 64);
                pr += __shfl_xor(pr, 4, 64);
                pr += __shfl_xor(pr, 8, 64);
                ov[j] = pr;
            }
            if (c16 == 0) {
                float4* o4 = (float4*)(out + (size_t)n*CC + kb*32 + quad*8);
                o4[0] = make_float4(ov[0], ov[1], ov[2], ov[3]);
                o4[1] = make_float4(ov[4], ov[5], ov[6], ov[7]);
            }
        }
    }
}

extern "C" void kernel_launch(void* const* d_in, const int* in_sizes, int n_in,
                              void* d_out, int out_size, void* d_ws, size_t ws_size,
                              hipStream_t stream)
{
    const float* q     = (const float*)d_in[0];
    const float* k     = (const float*)d_in[1];
    const float* v     = (const float*)d_in[2];
    const float* xyz   = (const float*)d_in[3];
    const int*   ridx  = (const int*)d_in[4];
    const float* Wq    = (const float*)d_in[5];
    const float* bq    = (const float*)d_in[6];
    const float* gq    = (const float*)d_in[7];
    const float* betaq = (const float*)d_in[8];
    const float* Wk    = (const float*)d_in[9];
    const float* bk    = (const float*)d_in[10];
    const float* gk    = (const float*)d_in[11];
    const float* betak = (const float*)d_in[12];
    const float* Wv    = (const float*)d_in[13];
    const float* bv    = (const float*)d_in[14];
    const float* Wp1   = (const float*)d_in[15];
    const float* bp1   = (const float*)d_in[16];
    const float* gp    = (const float*)d_in[17];
    const float* betap = (const float*)d_in[18];
    const float* Wp2   = (const float*)d_in[19];
    const float* bp2   = (const float*)d_in[20];
    const float* Ww1   = (const float*)d_in[21];
    const float* bw1   = (const float*)d_in[22];
    const float* gw    = (const float*)d_in[23];
    const float* betaw = (const float*)d_in[24];
    const float* Ww2   = (const float*)d_in[25];
    const float* bw2   = (const float*)d_in[26];
    float* out = (float*)d_out;

    float* ws = (float*)d_ws;
    float* queryw = ws;                           // [N, C]
    float* keyw   = ws + (size_t)NN*CC;           // [N, C]
    float* valw   = ws + 2*(size_t)NN*CC;         // [N, C]

    qkv_mfma<<<dim3(209, 3, 1), 256, 0, stream>>>(
        q, k, v, Wq, bq, gq, betaq, Wk, bk, gk, betak, Wv, bv,
        queryw, keyw, valw);

    attn_mfma<<<dim3(2500, 1, 1), 256, 0, stream>>>(
        xyz, ridx, Wp1, bp1, gp, betap, Wp2, bp2,
        Ww1, bw1, gw, betaw, Ww2, bw2,
        queryw, keyw, valw, out);
}